// Round 7
// baseline (698.552 us; speedup 1.0000x reference)
//
#include <hip/hip_runtime.h>
#include <hip/hip_bf16.h>
#include <math.h>

#define BSZ   1024
#define TLEN  320
#define EEGC  64
#define GEOC  18
#define ECH   512    // 64*8
#define GCH   144    // 18*8
#define HID   32
#define KW    32
#define TT    32
#define NT    (TLEN/TT)   // 10

// ---- workspace layout (float offsets) ----
#define OFF_ENC  0
#define OFF_MOD  (OFF_ENC + BSZ*TLEN*HID)
#define OFF_DP   (OFF_MOD + BSZ*TLEN*HID)
#define OFF_CWE  (OFF_DP + BSZ*HID*10)           // conv weights eeg [c][k] (A1-folded)
#define OFF_CWG  (OFF_CWE + ECH*KW)
#define OFF_DWE  (OFF_CWG + GCH*KW)              // dense weights eeg [c][h] (A2-folded)
#define OFF_DWG  (OFF_DWE + ECH*HID)
#define OFF_BTE  (OFF_DWG + GCH*HID)
#define OFF_BTG  (OFF_BTE + HID)
#define OFF_GAM  (OFF_BTG + HID)

struct P29 { const float* p[29]; };
// 0 ecw 1 ecb 2 e1s 3 e1b 4 e1m 5 e1v 6 edw 7 edb 8 e2s 9 e2b 10 e2m 11 e2v
// 12 gcw 13 gcb 14 g1s 15 g1b 16 g1m 17 g1v 18 gdw 19 gdb 20 g2s 21 g2b 22 g2m 23 g2v
// 24 gamma 25 fc1w 26 fc1b 27 fc2w 28 fc2b

// ============================================================
// prep v2 (r6 form, measured-good). Unchanged.
// ============================================================
__global__ __launch_bounds__(256) void prep_kernel(P29 P, float* __restrict__ ws)
{
    __shared__ float pse[8][32];
    __shared__ float psg[8][32];
    const int tid = threadIdx.x;
    float* convW_e = ws + OFF_CWE;
    float* convW_g = ws + OFF_CWG;
    float* dW_e    = ws + OFF_DWE;
    float* dW_g    = ws + OFF_DWG;

    for (int i = tid; i < ECH * KW; i += 256) {
        int c = i >> 5, k = i & 31;
        float A1 = P.p[2][c] * rsqrtf(P.p[5][c] + 1e-5f);
        convW_e[c * KW + k] = P.p[0][(size_t)k * ECH + c] * A1;
    }
    for (int i = tid; i < GCH * KW; i += 256) {
        int c = i >> 5, k = i & 31;
        float A1 = P.p[14][c] * rsqrtf(P.p[17][c] + 1e-5f);
        convW_g[c * KW + k] = P.p[12][(size_t)k * GCH + c] * A1;
    }
    for (int i = tid; i < ECH * HID; i += 256) {
        int h = i & 31;
        float A2 = P.p[8][h] * rsqrtf(P.p[11][h] + 1e-5f);
        dW_e[i] = P.p[6][i] * A2;
    }
    for (int i = tid; i < GCH * HID; i += 256) {
        int h = i & 31;
        float A2 = P.p[20][h] * rsqrtf(P.p[23][h] + 1e-5f);
        dW_g[i] = P.p[18][i] * A2;
    }
    for (int i = tid; i < HID; i += 256) ws[OFF_GAM + i] = P.p[24][i];

    // ---- bias partial sums: thread (part = tid>>5, h = tid&31) ----
    {
        const int h = tid & 31, part = tid >> 5;
        float s = 0.f;
        for (int c = part * 64; c < part * 64 + 64; ++c) {
            float A1 = P.p[2][c] * rsqrtf(P.p[5][c] + 1e-5f);
            float C1 = (P.p[1][c] - P.p[4][c]) * A1 + P.p[3][c];
            s += C1 * P.p[6][(size_t)c * HID + h];
        }
        pse[part][h] = s;
        float sg = 0.f;
        for (int c = part * 18; c < part * 18 + 18; ++c) {
            float A1 = P.p[14][c] * rsqrtf(P.p[17][c] + 1e-5f);
            float C1 = (P.p[13][c] - P.p[16][c]) * A1 + P.p[15][c];
            sg += C1 * P.p[18][(size_t)c * HID + h];
        }
        psg[part][h] = sg;
    }
    __syncthreads();
    if (tid < HID) {
        int h = tid;
        float A2 = P.p[8][h] * rsqrtf(P.p[11][h] + 1e-5f);
        float s = pse[0][h] + pse[1][h] + pse[2][h] + pse[3][h]
                + pse[4][h] + pse[5][h] + pse[6][h] + pse[7][h];
        ws[OFF_BTE + h] = A2 * (s + P.p[7][h] - P.p[10][h]) + P.p[9][h];
    } else if (tid >= 64 && tid < 64 + HID) {
        int h = tid - 64;
        float A2 = P.p[20][h] * rsqrtf(P.p[23][h] + 1e-5f);
        float s = psg[0][h] + psg[1][h] + psg[2][h] + psg[3][h]
                + psg[4][h] + psg[5][h] + psg[6][h] + psg[7][h];
        ws[OFF_BTG + h] = A2 * (s + P.p[19][h] - P.p[22][h]) + P.p[21][h];
    }
}

// conv inner: stream 12 b128 chunks of the 47-wide window with 1-deep
// lookahead; per-t FMA order is j (=t+k) ascending == k ascending:
// bit-identical to the scalar version.
__device__ __forceinline__ void conv_stream(const float4* __restrict__ xp4,
                                            const float* __restrict__ w,
                                            float* __restrict__ acc)
{
    float4 cur = xp4[0];
    #pragma unroll
    for (int j4 = 0; j4 < 12; ++j4) {
        float4 nxt = (j4 < 11) ? xp4[j4 + 1] : cur;
        #pragma unroll
        for (int i2 = 0; i2 < 4; ++i2) {
            const int i = j4 * 4 + i2;
            const float xv = (i2 == 0) ? cur.x : (i2 == 1) ? cur.y
                           : (i2 == 2) ? cur.z : cur.w;
            const int tlo = (i - 31 > 0) ? (i - 31) : 0;
            const int thi = (i < 15) ? i : 15;
            #pragma unroll
            for (int t = tlo; t <= thi; ++t)
                acc[t] = fmaf(xv, w[i - t], acc[t]);
        }
        cur = nxt;
    }
}

// ============================================================
// EEG path: r4-r6 measured-good body, ONE change: launch bound hint
// (256,4) -> (256). Occupancy was pinned at ~44% (=16 waves/CU) in
// BOTH the 4-block-LDS (r0) and 7-block-LDS (r4-6) regimes -- the
// only common factor is the min-waves-per-EU=4 hint. Body compiles
// naturally to 52 VGPR, so removing the hint cannot raise pressure.
// path_geo keeps (256,4) as the within-run control.
// ============================================================
__global__ __launch_bounds__(256)
void path_eeg(const float* __restrict__ x, float* __restrict__ ws)
{
    __shared__ __align__(16) float xsT[16 * 68];   // [ch_loc][j], 4352 B
    __shared__ __align__(16) float czs[128 * 36];  // cz[128*36] / stash[256*16]

    const int b   = blockIdx.y;
    const int t0  = blockIdx.x * TT;
    const int tid = threadIdx.x;
    const float* convW = ws + OFF_CWE;
    const float* dW    = ws + OFF_DWE;
    float* enc         = ws + OFF_ENC;
    float* cz          = czs;

    const float* xb = x + (size_t)b * (TLEN * EEGC);

    const int tg = tid & 7, hg = (tid >> 3) & 7, q = tid >> 6;
    const int c_loc = tid & 127, th = tid >> 7;
    float a00=0,a01=0,a02=0,a03=0, a10=0,a11=0,a12=0,a13=0;
    float a20=0,a21=0,a22=0,a23=0, a30=0,a31=0,a32=0,a33=0;

    #pragma unroll 1
    for (int ph = 0; ph < 4; ++ph) {
        if (ph) __syncthreads();   // dense(ph-1) reads of cz done; xsT free
        // ---- stage this phase's 16-channel x-slice (transient regs) ----
        if (tid < 252) {
            const int sj = tid >> 2, sc4 = tid & 3;
            const int st = t0 - 15 + sj;
            float4 sv = make_float4(0.f, 0.f, 0.f, 0.f);
            if (st >= 0 && st < TLEN)
                sv = *(const float4*)(xb + (size_t)st * EEGC + ph * 16 + sc4 * 4);
            float* p = &xsT[(sc4 * 4) * 68 + sj];
            p[0] = sv.x; p[68] = sv.y; p[136] = sv.z; p[204] = sv.w;
        }
        __syncthreads();
        // ---- conv: channel c = ph*128 + c_loc, t's [th*16, th*16+16) ----
        {
            const int c   = ph * 128 + c_loc;
            const int chl = c_loc >> 3;          // local channel 0..15
            float w[KW];
            const float4* wp4 = (const float4*)(convW + c * KW);
            #pragma unroll
            for (int k4 = 0; k4 < 8; ++k4) {
                float4 v = wp4[k4];
                w[4*k4+0]=v.x; w[4*k4+1]=v.y; w[4*k4+2]=v.z; w[4*k4+3]=v.w;
            }
            float acc[16];
            #pragma unroll
            for (int t = 0; t < 16; ++t) acc[t] = 0.f;
            conv_stream((const float4*)(&xsT[chl * 68 + th * 16]), w, acc);
            float4* czp = (float4*)(cz + c_loc * 36 + th * 16);
            czp[0] = make_float4(acc[0],  acc[1],  acc[2],  acc[3]);
            czp[1] = make_float4(acc[4],  acc[5],  acc[6],  acc[7]);
            czp[2] = make_float4(acc[8],  acc[9],  acc[10], acc[11]);
            czp[3] = make_float4(acc[12], acc[13], acc[14], acc[15]);
        }
        __syncthreads();
        // ---- dense partial: my wave's 32-c chunk, pipelined loads ----
        {
            const float* dWh = dW + (size_t)(ph * 128 + q * 32) * HID + hg * 4;
            const float* czb = cz + (q * 32) * 36 + tg * 4;
            float4 wvb[4], cvb[2];
            wvb[0] = *(const float4*)(dWh + 0 * HID);
            wvb[1] = *(const float4*)(dWh + 1 * HID);
            wvb[2] = *(const float4*)(dWh + 2 * HID);
            wvb[3] = *(const float4*)(dWh + 3 * HID);
            cvb[0] = *(const float4*)(czb + 0 * 36);
            cvb[1] = *(const float4*)(czb + 1 * 36);
            #pragma unroll
            for (int ci = 0; ci < 32; ++ci) {
                float4 cv = cvb[ci & 1];
                float4 wv = wvb[ci & 3];
                if (ci + 2 < 32) cvb[ci & 1] = *(const float4*)(czb + (ci + 2) * 36);
                if (ci + 4 < 32) wvb[ci & 3] = *(const float4*)(dWh + (ci + 4) * HID);
                a00 = fmaf(cv.x, wv.x, a00); a01 = fmaf(cv.x, wv.y, a01);
                a02 = fmaf(cv.x, wv.z, a02); a03 = fmaf(cv.x, wv.w, a03);
                a10 = fmaf(cv.y, wv.x, a10); a11 = fmaf(cv.y, wv.y, a11);
                a12 = fmaf(cv.y, wv.z, a12); a13 = fmaf(cv.y, wv.w, a13);
                a20 = fmaf(cv.z, wv.x, a20); a21 = fmaf(cv.z, wv.y, a21);
                a22 = fmaf(cv.z, wv.z, a22); a23 = fmaf(cv.z, wv.w, a23);
                a30 = fmaf(cv.w, wv.x, a30); a31 = fmaf(cv.w, wv.y, a31);
                a32 = fmaf(cv.w, wv.z, a32); a33 = fmaf(cv.w, wv.w, a33);
            }
        }
    }

    // ---- 4-chunk reduction via LDS (stash stride 16, XOR group swizzle) ----
    __syncthreads();
    float* stash = czs;   // 256*16 = 4096 floats (fits in cz region)
    {
        const int s = (tid >> 1) & 3;
        float4* sp = (float4*)(stash + tid * 16);
        sp[s ^ 0] = make_float4(a00,a01,a02,a03);
        sp[s ^ 1] = make_float4(a10,a11,a12,a13);
        sp[s ^ 2] = make_float4(a20,a21,a22,a23);
        sp[s ^ 3] = make_float4(a30,a31,a32,a33);
    }
    __syncthreads();
    {
        const int t = tid >> 3, hq = tid & 7;
        const int pg = (t & 3) ^ (t >> 3);   // (partner>>1)&3 == t>>3
        float4 v = make_float4(0.f,0.f,0.f,0.f);
        #pragma unroll
        for (int qq = 0; qq < 4; ++qq) {
            const int partner = qq * 64 + hq * 8 + (t >> 2);
            float4 s = *(const float4*)(stash + partner * 16 + pg * 4);
            v.x += s.x; v.y += s.y; v.z += s.z; v.w += s.w;
        }
        float4 bias = *(const float4*)(ws + OFF_BTE + hq * 4);
        v.x = fmaxf(v.x + bias.x, 0.f);
        v.y = fmaxf(v.y + bias.y, 0.f);
        v.z = fmaxf(v.z + bias.z, 0.f);
        v.w = fmaxf(v.w + bias.w, 0.f);
        *(float4*)(enc + ((size_t)(b * TLEN + t0 + t)) * HID + hq * 4) = v;
    }
}

// ============================================================
// GEO path v2 (r5/r6 form, passed). UNCHANGED — keeps (256,4) as the
// within-run occupancy control vs path_eeg's removed hint.
// ============================================================
__device__ __forceinline__ void geo_conv_unit(const float* __restrict__ convW,
                                              const float* __restrict__ xsT,
                                              float* __restrict__ cz,
                                              int c, int th)
{
    float w[KW];
    const float4* wp4 = (const float4*)(convW + c * KW);
    #pragma unroll
    for (int k4 = 0; k4 < 8; ++k4) {
        float4 v = wp4[k4];
        w[4*k4+0]=v.x; w[4*k4+1]=v.y; w[4*k4+2]=v.z; w[4*k4+3]=v.w;
    }
    float acc[16];
    #pragma unroll
    for (int t = 0; t < 16; ++t) acc[t] = 0.f;
    conv_stream((const float4*)(xsT + (c >> 3) * 68 + th * 16), w, acc);
    float4* czp = (float4*)(cz + c * 36 + th * 16);
    czp[0] = make_float4(acc[0],  acc[1],  acc[2],  acc[3]);
    czp[1] = make_float4(acc[4],  acc[5],  acc[6],  acc[7]);
    czp[2] = make_float4(acc[8],  acc[9],  acc[10], acc[11]);
    czp[3] = make_float4(acc[12], acc[13], acc[14], acc[15]);
}

__global__ __launch_bounds__(256, 4) void path_geo(const float* __restrict__ x,
                                                   float* __restrict__ ws)
{
    __shared__ __align__(16) float xsT[GEOC * 68];  // [ch][j], 4896 B
    __shared__ __align__(16) float cz[GCH * 36];    // 20736 B (stash 5120 fits)

    const int b   = blockIdx.y;
    const int t0  = blockIdx.x * TT;
    const int tid = threadIdx.x;
    const float* convW = ws + OFF_CWG;
    const float* dW    = ws + OFF_DWG;
    float* mod         = ws + OFF_MOD;

    const float* xb = x + (size_t)b * (TLEN * GEOC);
    for (int i = tid; i < 63 * GEOC; i += 256) {
        int j = i / GEOC, ch = i - j * GEOC;
        int t = t0 - 15 + j;
        xsT[ch * 68 + j] = (t >= 0 && t < TLEN) ? xb[(size_t)t * GEOC + ch] : 0.f;
    }
    __syncthreads();

    geo_conv_unit(convW, xsT, cz, tid >> 1, tid & 1);
    if (tid < 32)
        geo_conv_unit(convW, xsT, cz, 128 + (tid >> 1), tid & 1);
    __syncthreads();

    const int tg = tid & 7, hg = (tid >> 3) & 7, q = tid >> 6;
    float a00=0,a01=0,a02=0,a03=0, a10=0,a11=0,a12=0,a13=0;
    float a20=0,a21=0,a22=0,a23=0, a30=0,a31=0,a32=0,a33=0;
    {
        const float* dWh = dW + (size_t)(q * 36) * HID + hg * 4;
        const float* czb = cz + (q * 36) * 36 + tg * 4;
        #pragma unroll 2
        for (int ci = 0; ci < 36; ++ci) {
            float4 cv = *(const float4*)(czb + ci * 36);
            float4 wv = *(const float4*)(dWh + ci * HID);
            a00 = fmaf(cv.x, wv.x, a00); a01 = fmaf(cv.x, wv.y, a01);
            a02 = fmaf(cv.x, wv.z, a02); a03 = fmaf(cv.x, wv.w, a03);
            a10 = fmaf(cv.y, wv.x, a10); a11 = fmaf(cv.y, wv.y, a11);
            a12 = fmaf(cv.y, wv.z, a12); a13 = fmaf(cv.y, wv.w, a13);
            a20 = fmaf(cv.z, wv.x, a20); a21 = fmaf(cv.z, wv.y, a21);
            a22 = fmaf(cv.z, wv.z, a22); a23 = fmaf(cv.z, wv.w, a23);
            a30 = fmaf(cv.w, wv.x, a30); a31 = fmaf(cv.w, wv.y, a31);
            a32 = fmaf(cv.w, wv.z, a32); a33 = fmaf(cv.w, wv.w, a33);
        }
    }
    __syncthreads();
    float* stash = cz;
    {
        float4* sp = (float4*)(stash + tid * 20);
        sp[0] = make_float4(a00,a01,a02,a03);
        sp[1] = make_float4(a10,a11,a12,a13);
        sp[2] = make_float4(a20,a21,a22,a23);
        sp[3] = make_float4(a30,a31,a32,a33);
    }
    __syncthreads();
    {
        const int t = tid >> 3, hq = tid & 7;
        float4 v = make_float4(0.f,0.f,0.f,0.f);
        #pragma unroll
        for (int qq = 0; qq < 4; ++qq) {
            const int partner = qq * 64 + hq * 8 + (t >> 2);
            float4 s = *(const float4*)(stash + partner * 20 + (t & 3) * 4);
            v.x += s.x; v.y += s.y; v.z += s.z; v.w += s.w;
        }
        float4 bias = *(const float4*)(ws + OFF_BTG + hq * 4);
        v.x = 1.f / (1.f + expf(-(v.x + bias.x)));
        v.y = 1.f / (1.f + expf(-(v.y + bias.y)));
        v.z = 1.f / (1.f + expf(-(v.z + bias.z)));
        v.w = 1.f / (1.f + expf(-(v.w + bias.w)));
        *(float4*)(mod + ((size_t)(b * TLEN + t0 + t)) * HID + hq * 4) = v;
    }
}

// ============================================================
// Fused scan+head. 256 blocks x 128 threads; group g = tid>>5 owns
// b = blk*4+g. Scan body is r6's register-double-buffered form,
// textually identical arithmetic; dp goes to LDS instead of global.
// Then fc1 (all 128 threads x 4 b's, dp broadcast from LDS) + ELU,
// then fc2 on threads 0..15. Kills the head launch + dp round-trip.
// ============================================================
#define SSTEP(CE, CG) { \
    const float ce = (CE), cg = (CG); \
    m1 = 0.9f * m1 + ce; float s1 = ((m1 - 0.7f) >= 0.f) ? 1.f : 0.f; m1 = m1 * (1.f - s1); \
    m2 = 0.8f * m2 + ce; float s2 = ((m2 - 0.5f) >= 0.f) ? 1.f : 0.f; m2 = m2 * (1.f - s2); \
    m3 = 0.6f * m3 + ce; float s3 = ((m3 - 0.3f) >= 0.f) ? 1.f : 0.f; m3 = m3 * (1.f - s3); \
    const float hr = (s1 + s2 + s3) / 3.0f; \
    eta = 0.36f * eta + 0.64f * prev; \
    const float theta = 0.5f + 1.8f * eta - g * cg; \
    ma = 0.8f * ma + hr; \
    const float sa = ((ma - theta) >= 0.f) ? 1.f : 0.f; \
    ma = ma * (1.f - sa); \
    mli = 0.9f * mli + sa; \
    prev = sa; }

__global__ __launch_bounds__(128) void scan_head_kernel(
    float* __restrict__ ws,
    const float* __restrict__ f1w, const float* __restrict__ f1b,
    const float* __restrict__ f2w, const float* __restrict__ f2b,
    float* __restrict__ out)
{
    __shared__ __align__(16) float dps[4][320];
    __shared__ float act[4][128];
    const int tid = threadIdx.x;
    const int grp = tid >> 5, h = tid & 31;
    const int b = blockIdx.x * 4 + grp;

    // ---- scan for (b, h) ----
    {
        const float g = ws[OFF_GAM + h];
        const float* pe = ws + OFF_ENC + (size_t)b * TLEN * HID + h;
        const float* pg = ws + OFF_MOD + (size_t)b * TLEN * HID + h;
        float* dpp = &dps[grp][h * 10];

        float m1 = 0.f, m2 = 0.f, m3 = 0.f, ma = 0.f, eta = 0.f, mli = 0.f, prev = 0.f;
        float acc_lo = 0.f, acc_hi = 0.f;
        float ceA[16], cgA[16], ceB[16], cgB[16];

        #pragma unroll
        for (int i = 0; i < 16; ++i) { ceA[i] = pe[i * HID]; cgA[i] = pg[i * HID]; }

        #pragma unroll 1
        for (int ch = 0; ch < 20; ch += 2) {
            const int baseB = (ch + 1) * 16;
            #pragma unroll
            for (int i = 0; i < 16; ++i) {
                ceB[i] = pe[(baseB + i) * HID];
                cgB[i] = pg[(baseB + i) * HID];
            }
            #pragma unroll
            for (int i = 0; i < 16; ++i) {       // t&31 = i < 16 -> lo
                SSTEP(ceA[i], cgA[i]);
                acc_lo += mli;
            }
            if (ch + 2 < 20) {
                const int baseA = (ch + 2) * 16;
                #pragma unroll
                for (int i = 0; i < 16; ++i) {
                    ceA[i] = pe[(baseA + i) * HID];
                    cgA[i] = pg[(baseA + i) * HID];
                }
            }
            #pragma unroll
            for (int i = 0; i < 16; ++i) {       // t&31 = 16+i -> hi
                SSTEP(ceB[i], cgB[i]);
                acc_hi += mli;
            }
            dpp[ch >> 1] = acc_hi * (1.f / 16.f) - acc_lo * (1.f / 16.f);
            acc_lo = 0.f; acc_hi = 0.f;
        }
    }
    __syncthreads();

    // ---- fc1 + ELU: thread j = tid, for each of the block's 4 b's ----
    {
        const int j = tid;
        #pragma unroll 1
        for (int gb = 0; gb < 4; ++gb) {
            const float* dpb = dps[gb];
            float a0 = 0.f, a1 = 0.f, a2 = 0.f, a3 = 0.f;
            #pragma unroll 4
            for (int i = 0; i < 320; i += 4) {
                a0 = fmaf(dpb[i + 0], f1w[(i + 0) * 128 + j], a0);
                a1 = fmaf(dpb[i + 1], f1w[(i + 1) * 128 + j], a1);
                a2 = fmaf(dpb[i + 2], f1w[(i + 2) * 128 + j], a2);
                a3 = fmaf(dpb[i + 3], f1w[(i + 3) * 128 + j], a3);
            }
            float a = f1b[j] + ((a0 + a1) + (a2 + a3));
            act[gb][j] = (a > 0.f) ? a : expm1f(a);   // ELU, alpha=1
        }
    }
    __syncthreads();

    // ---- fc2: threads 0..15 -> (gb = tid>>2, out j = tid&3) ----
    if (tid < 16) {
        const int gb = tid >> 2, j = tid & 3;
        float o = f2b[j];
        for (int jj = 0; jj < 128; ++jj)
            o = fmaf(act[gb][jj], f2w[jj * 4 + j], o);
        out[(blockIdx.x * 4 + gb) * 4 + j] = o;
    }
}

// ============================================================
extern "C" void kernel_launch(void* const* d_in, const int* in_sizes, int n_in,
                              void* d_out, int out_size, void* d_ws, size_t ws_size,
                              hipStream_t stream)
{
    float* ws = (float*)d_ws;

    P29 P;
    for (int k = 0; k < 29; ++k) P.p[k] = (const float*)d_in[k + 2];
    prep_kernel<<<1, 256, 0, stream>>>(P, ws);

    path_eeg<<<dim3(NT, BSZ), 256, 0, stream>>>((const float*)d_in[0], ws);
    path_geo<<<dim3(NT, BSZ), 256, 0, stream>>>((const float*)d_in[1], ws);

    scan_head_kernel<<<BSZ / 4, 128, 0, stream>>>(
        ws, (const float*)d_in[27], (const float*)d_in[28],
        (const float*)d_in[29], (const float*)d_in[30], (float*)d_out);
}

// Round 8
// 673.820 us; speedup vs baseline: 1.0367x; 1.0367x over previous
//
#include <hip/hip_runtime.h>
#include <hip/hip_bf16.h>
#include <math.h>

#define BSZ   1024
#define TLEN  320
#define EEGC  64
#define GEOC  18
#define ECH   512    // 64*8
#define GCH   144    // 18*8
#define HID   32
#define KW    32
#define TT    32
#define NT    (TLEN/TT)   // 10

// ---- workspace layout (float offsets) ----
#define OFF_ENC  0
#define OFF_MOD  (OFF_ENC + BSZ*TLEN*HID)
#define OFF_DP   (OFF_MOD + BSZ*TLEN*HID)
#define OFF_CWE  (OFF_DP + BSZ*HID*10)           // conv weights eeg [c][k] (A1-folded)
#define OFF_CWG  (OFF_CWE + ECH*KW)
#define OFF_DWE  (OFF_CWG + GCH*KW)              // dense weights eeg [c][h] (A2-folded)
#define OFF_DWG  (OFF_DWE + ECH*HID)
#define OFF_BTE  (OFF_DWG + GCH*HID)
#define OFF_BTG  (OFF_BTE + HID)
#define OFF_GAM  (OFF_BTG + HID)

struct P29 { const float* p[29]; };
// 0 ecw 1 ecb 2 e1s 3 e1b 4 e1m 5 e1v 6 edw 7 edb 8 e2s 9 e2b 10 e2m 11 e2v
// 12 gcw 13 gcb 14 g1s 15 g1b 16 g1m 17 g1v 18 gdw 19 gdb 20 g2s 21 g2b 22 g2m 23 g2v
// 24 gamma 25 fc1w 26 fc1b 27 fc2w 28 fc2b

// ============================================================
// prep v3: elementwise weight folds spread over 33 blocks (block-
// strided, bit-identical per element); block 0 additionally does the
// bias reductions (r6 parallel form, bit-identical) + gamma.
// Was one block on one CU ~30 us serial; now ~5-10 us.
// ============================================================
__global__ __launch_bounds__(256) void prep_kernel(P29 P, float* __restrict__ ws)
{
    __shared__ float pse[8][32];
    __shared__ float psg[8][32];
    const int tid = threadIdx.x;
    const int gid = blockIdx.x * 256 + tid;
    const int gstride = 33 * 256;
    float* convW_e = ws + OFF_CWE;
    float* convW_g = ws + OFF_CWG;
    float* dW_e    = ws + OFF_DWE;
    float* dW_g    = ws + OFF_DWG;

    for (int i = gid; i < ECH * KW; i += gstride) {
        int c = i >> 5, k = i & 31;
        float A1 = P.p[2][c] * rsqrtf(P.p[5][c] + 1e-5f);
        convW_e[c * KW + k] = P.p[0][(size_t)k * ECH + c] * A1;
    }
    for (int i = gid; i < GCH * KW; i += gstride) {
        int c = i >> 5, k = i & 31;
        float A1 = P.p[14][c] * rsqrtf(P.p[17][c] + 1e-5f);
        convW_g[c * KW + k] = P.p[12][(size_t)k * GCH + c] * A1;
    }
    for (int i = gid; i < ECH * HID; i += gstride) {
        int h = i & 31;
        float A2 = P.p[8][h] * rsqrtf(P.p[11][h] + 1e-5f);
        dW_e[i] = P.p[6][i] * A2;
    }
    for (int i = gid; i < GCH * HID; i += gstride) {
        int h = i & 31;
        float A2 = P.p[20][h] * rsqrtf(P.p[23][h] + 1e-5f);
        dW_g[i] = P.p[18][i] * A2;
    }
    for (int i = gid; i < HID; i += gstride) ws[OFF_GAM + i] = P.p[24][i];

    if (blockIdx.x == 0) {
        // ---- bias partial sums: thread (part = tid>>5, h = tid&31) ----
        {
            const int h = tid & 31, part = tid >> 5;
            float s = 0.f;
            for (int c = part * 64; c < part * 64 + 64; ++c) {
                float A1 = P.p[2][c] * rsqrtf(P.p[5][c] + 1e-5f);
                float C1 = (P.p[1][c] - P.p[4][c]) * A1 + P.p[3][c];
                s += C1 * P.p[6][(size_t)c * HID + h];
            }
            pse[part][h] = s;
            float sg = 0.f;
            for (int c = part * 18; c < part * 18 + 18; ++c) {
                float A1 = P.p[14][c] * rsqrtf(P.p[17][c] + 1e-5f);
                float C1 = (P.p[13][c] - P.p[16][c]) * A1 + P.p[15][c];
                sg += C1 * P.p[18][(size_t)c * HID + h];
            }
            psg[part][h] = sg;
        }
        __syncthreads();
        if (tid < HID) {
            int h = tid;
            float A2 = P.p[8][h] * rsqrtf(P.p[11][h] + 1e-5f);
            float s = pse[0][h] + pse[1][h] + pse[2][h] + pse[3][h]
                    + pse[4][h] + pse[5][h] + pse[6][h] + pse[7][h];
            ws[OFF_BTE + h] = A2 * (s + P.p[7][h] - P.p[10][h]) + P.p[9][h];
        } else if (tid >= 64 && tid < 64 + HID) {
            int h = tid - 64;
            float A2 = P.p[20][h] * rsqrtf(P.p[23][h] + 1e-5f);
            float s = psg[0][h] + psg[1][h] + psg[2][h] + psg[3][h]
                    + psg[4][h] + psg[5][h] + psg[6][h] + psg[7][h];
            ws[OFF_BTG + h] = A2 * (s + P.p[19][h] - P.p[22][h]) + P.p[21][h];
        }
    }
}

// conv inner: stream 12 b128 chunks of the 47-wide window with 1-deep
// lookahead; per-t FMA order is j (=t+k) ascending == k ascending:
// bit-identical to the scalar version.
__device__ __forceinline__ void conv_stream(const float4* __restrict__ xp4,
                                            const float* __restrict__ w,
                                            float* __restrict__ acc)
{
    float4 cur = xp4[0];
    #pragma unroll
    for (int j4 = 0; j4 < 12; ++j4) {
        float4 nxt = (j4 < 11) ? xp4[j4 + 1] : cur;
        #pragma unroll
        for (int i2 = 0; i2 < 4; ++i2) {
            const int i = j4 * 4 + i2;
            const float xv = (i2 == 0) ? cur.x : (i2 == 1) ? cur.y
                           : (i2 == 2) ? cur.z : cur.w;
            const int tlo = (i - 31 > 0) ? (i - 31) : 0;
            const int thi = (i < 15) ? i : 15;
            #pragma unroll
            for (int t = tlo; t <= thi; ++t)
                acc[t] = fmaf(xv, w[i - t], acc[t]);
        }
        cur = nxt;
    }
}

__device__ __forceinline__ void geo_conv_unit(const float* __restrict__ convW,
                                              const float* __restrict__ xsT,
                                              float* __restrict__ cz,
                                              int c, int th)
{
    float w[KW];
    const float4* wp4 = (const float4*)(convW + c * KW);
    #pragma unroll
    for (int k4 = 0; k4 < 8; ++k4) {
        float4 v = wp4[k4];
        w[4*k4+0]=v.x; w[4*k4+1]=v.y; w[4*k4+2]=v.z; w[4*k4+3]=v.w;
    }
    float acc[16];
    #pragma unroll
    for (int t = 0; t < 16; ++t) acc[t] = 0.f;
    conv_stream((const float4*)(xsT + (c >> 3) * 68 + th * 16), w, acc);
    float4* czp = (float4*)(cz + c * 36 + th * 16);
    czp[0] = make_float4(acc[0],  acc[1],  acc[2],  acc[3]);
    czp[1] = make_float4(acc[4],  acc[5],  acc[6],  acc[7]);
    czp[2] = make_float4(acc[8],  acc[9],  acc[10], acc[11]);
    czp[3] = make_float4(acc[12], acc[13], acc[14], acc[15]);
}

// ============================================================
// Merged path kernel. Grid (2*NT, BSZ); x<NT -> EEG body (r4-r7
// measured-good, byte-identical math), else GEO body (r5-r7 form).
// Same-stream kernels serialize, so the only way to let geo's light
// blocks fill eeg's idle issue slots (VALUBusy 51%) is one launch.
// x is the fastest dispatch dim -> each y row contributes 10 eeg +
// 10 geo blocks, interleaved on CUs throughout the run.
// LDS: union buffer 6408 floats = 25632 B -> 6 blocks/CU.
//   eeg: xsT = smem[0..1088), czs = smem[1088..5696)
//   geo: xsT = smem[0..1224), cz  = smem[1224..6408)
// Register tripwire: both branches peak ~52-64 VGPR exclusively; if
// the merged allocation crosses the 64 tier the spill shows as
// FETCH_SIZE in GBs (r2/r3 signature) -> revert to split kernels.
// ============================================================
__global__ __launch_bounds__(256)
void path_both(const float* __restrict__ xe, const float* __restrict__ xg,
               float* __restrict__ ws)
{
    __shared__ __align__(16) float smem[6408];

    const int b   = blockIdx.y;
    const int tid = threadIdx.x;

    if (blockIdx.x < NT) {
        // ================= EEG =================
        const int t0 = blockIdx.x * TT;
        float* xsT = smem;            // 16*68 = 1088
        float* cz  = smem + 1088;     // 128*36 = 4608
        const float* convW = ws + OFF_CWE;
        const float* dW    = ws + OFF_DWE;
        float* enc         = ws + OFF_ENC;

        const float* xb = xe + (size_t)b * (TLEN * EEGC);

        const int tg = tid & 7, hg = (tid >> 3) & 7, q = tid >> 6;
        const int c_loc = tid & 127, th = tid >> 7;
        float a00=0,a01=0,a02=0,a03=0, a10=0,a11=0,a12=0,a13=0;
        float a20=0,a21=0,a22=0,a23=0, a30=0,a31=0,a32=0,a33=0;

        #pragma unroll 1
        for (int ph = 0; ph < 4; ++ph) {
            if (ph) __syncthreads();
            // ---- stage this phase's 16-channel x-slice (transient regs) ----
            if (tid < 252) {
                const int sj = tid >> 2, sc4 = tid & 3;
                const int st = t0 - 15 + sj;
                float4 sv = make_float4(0.f, 0.f, 0.f, 0.f);
                if (st >= 0 && st < TLEN)
                    sv = *(const float4*)(xb + (size_t)st * EEGC + ph * 16 + sc4 * 4);
                float* p = &xsT[(sc4 * 4) * 68 + sj];
                p[0] = sv.x; p[68] = sv.y; p[136] = sv.z; p[204] = sv.w;
            }
            __syncthreads();
            // ---- conv ----
            {
                const int c   = ph * 128 + c_loc;
                const int chl = c_loc >> 3;
                float w[KW];
                const float4* wp4 = (const float4*)(convW + c * KW);
                #pragma unroll
                for (int k4 = 0; k4 < 8; ++k4) {
                    float4 v = wp4[k4];
                    w[4*k4+0]=v.x; w[4*k4+1]=v.y; w[4*k4+2]=v.z; w[4*k4+3]=v.w;
                }
                float acc[16];
                #pragma unroll
                for (int t = 0; t < 16; ++t) acc[t] = 0.f;
                conv_stream((const float4*)(&xsT[chl * 68 + th * 16]), w, acc);
                float4* czp = (float4*)(cz + c_loc * 36 + th * 16);
                czp[0] = make_float4(acc[0],  acc[1],  acc[2],  acc[3]);
                czp[1] = make_float4(acc[4],  acc[5],  acc[6],  acc[7]);
                czp[2] = make_float4(acc[8],  acc[9],  acc[10], acc[11]);
                czp[3] = make_float4(acc[12], acc[13], acc[14], acc[15]);
            }
            __syncthreads();
            // ---- dense partial ----
            {
                const float* dWh = dW + (size_t)(ph * 128 + q * 32) * HID + hg * 4;
                const float* czb = cz + (q * 32) * 36 + tg * 4;
                float4 wvb[4], cvb[2];
                wvb[0] = *(const float4*)(dWh + 0 * HID);
                wvb[1] = *(const float4*)(dWh + 1 * HID);
                wvb[2] = *(const float4*)(dWh + 2 * HID);
                wvb[3] = *(const float4*)(dWh + 3 * HID);
                cvb[0] = *(const float4*)(czb + 0 * 36);
                cvb[1] = *(const float4*)(czb + 1 * 36);
                #pragma unroll
                for (int ci = 0; ci < 32; ++ci) {
                    float4 cv = cvb[ci & 1];
                    float4 wv = wvb[ci & 3];
                    if (ci + 2 < 32) cvb[ci & 1] = *(const float4*)(czb + (ci + 2) * 36);
                    if (ci + 4 < 32) wvb[ci & 3] = *(const float4*)(dWh + (ci + 4) * HID);
                    a00 = fmaf(cv.x, wv.x, a00); a01 = fmaf(cv.x, wv.y, a01);
                    a02 = fmaf(cv.x, wv.z, a02); a03 = fmaf(cv.x, wv.w, a03);
                    a10 = fmaf(cv.y, wv.x, a10); a11 = fmaf(cv.y, wv.y, a11);
                    a12 = fmaf(cv.y, wv.z, a12); a13 = fmaf(cv.y, wv.w, a13);
                    a20 = fmaf(cv.z, wv.x, a20); a21 = fmaf(cv.z, wv.y, a21);
                    a22 = fmaf(cv.z, wv.z, a22); a23 = fmaf(cv.z, wv.w, a23);
                    a30 = fmaf(cv.w, wv.x, a30); a31 = fmaf(cv.w, wv.y, a31);
                    a32 = fmaf(cv.w, wv.z, a32); a33 = fmaf(cv.w, wv.w, a33);
                }
            }
        }

        // ---- 4-chunk reduction (stash stride 16, XOR group swizzle) ----
        __syncthreads();
        float* stash = cz;   // 256*16 = 4096 floats
        {
            const int s = (tid >> 1) & 3;
            float4* sp = (float4*)(stash + tid * 16);
            sp[s ^ 0] = make_float4(a00,a01,a02,a03);
            sp[s ^ 1] = make_float4(a10,a11,a12,a13);
            sp[s ^ 2] = make_float4(a20,a21,a22,a23);
            sp[s ^ 3] = make_float4(a30,a31,a32,a33);
        }
        __syncthreads();
        {
            const int t = tid >> 3, hq = tid & 7;
            const int pg = (t & 3) ^ (t >> 3);
            float4 v = make_float4(0.f,0.f,0.f,0.f);
            #pragma unroll
            for (int qq = 0; qq < 4; ++qq) {
                const int partner = qq * 64 + hq * 8 + (t >> 2);
                float4 s = *(const float4*)(stash + partner * 16 + pg * 4);
                v.x += s.x; v.y += s.y; v.z += s.z; v.w += s.w;
            }
            float4 bias = *(const float4*)(ws + OFF_BTE + hq * 4);
            v.x = fmaxf(v.x + bias.x, 0.f);
            v.y = fmaxf(v.y + bias.y, 0.f);
            v.z = fmaxf(v.z + bias.z, 0.f);
            v.w = fmaxf(v.w + bias.w, 0.f);
            *(float4*)(enc + ((size_t)(b * TLEN + t0 + t)) * HID + hq * 4) = v;
        }
    } else {
        // ================= GEO =================
        const int t0 = (blockIdx.x - NT) * TT;
        float* xsT = smem;            // 18*68 = 1224
        float* cz  = smem + 1224;     // 144*36 = 5184
        const float* convW = ws + OFF_CWG;
        const float* dW    = ws + OFF_DWG;
        float* mod         = ws + OFF_MOD;

        const float* xb = xg + (size_t)b * (TLEN * GEOC);
        for (int i = tid; i < 63 * GEOC; i += 256) {
            int j = i / GEOC, ch = i - j * GEOC;
            int t = t0 - 15 + j;
            xsT[ch * 68 + j] = (t >= 0 && t < TLEN) ? xb[(size_t)t * GEOC + ch] : 0.f;
        }
        __syncthreads();

        geo_conv_unit(convW, xsT, cz, tid >> 1, tid & 1);
        if (tid < 32)
            geo_conv_unit(convW, xsT, cz, 128 + (tid >> 1), tid & 1);
        __syncthreads();

        const int tg = tid & 7, hg = (tid >> 3) & 7, q = tid >> 6;
        float a00=0,a01=0,a02=0,a03=0, a10=0,a11=0,a12=0,a13=0;
        float a20=0,a21=0,a22=0,a23=0, a30=0,a31=0,a32=0,a33=0;
        {
            const float* dWh = dW + (size_t)(q * 36) * HID + hg * 4;
            const float* czb = cz + (q * 36) * 36 + tg * 4;
            #pragma unroll 2
            for (int ci = 0; ci < 36; ++ci) {
                float4 cv = *(const float4*)(czb + ci * 36);
                float4 wv = *(const float4*)(dWh + ci * HID);
                a00 = fmaf(cv.x, wv.x, a00); a01 = fmaf(cv.x, wv.y, a01);
                a02 = fmaf(cv.x, wv.z, a02); a03 = fmaf(cv.x, wv.w, a03);
                a10 = fmaf(cv.y, wv.x, a10); a11 = fmaf(cv.y, wv.y, a11);
                a12 = fmaf(cv.y, wv.z, a12); a13 = fmaf(cv.y, wv.w, a13);
                a20 = fmaf(cv.z, wv.x, a20); a21 = fmaf(cv.z, wv.y, a21);
                a22 = fmaf(cv.z, wv.z, a22); a23 = fmaf(cv.z, wv.w, a23);
                a30 = fmaf(cv.w, wv.x, a30); a31 = fmaf(cv.w, wv.y, a31);
                a32 = fmaf(cv.w, wv.z, a32); a33 = fmaf(cv.w, wv.w, a33);
            }
        }
        __syncthreads();
        float* stash = cz;
        {
            float4* sp = (float4*)(stash + tid * 20);
            sp[0] = make_float4(a00,a01,a02,a03);
            sp[1] = make_float4(a10,a11,a12,a13);
            sp[2] = make_float4(a20,a21,a22,a23);
            sp[3] = make_float4(a30,a31,a32,a33);
        }
        __syncthreads();
        {
            const int t = tid >> 3, hq = tid & 7;
            float4 v = make_float4(0.f,0.f,0.f,0.f);
            #pragma unroll
            for (int qq = 0; qq < 4; ++qq) {
                const int partner = qq * 64 + hq * 8 + (t >> 2);
                float4 s = *(const float4*)(stash + partner * 20 + (t & 3) * 4);
                v.x += s.x; v.y += s.y; v.z += s.z; v.w += s.w;
            }
            float4 bias = *(const float4*)(ws + OFF_BTG + hq * 4);
            v.x = 1.f / (1.f + expf(-(v.x + bias.x)));
            v.y = 1.f / (1.f + expf(-(v.y + bias.y)));
            v.z = 1.f / (1.f + expf(-(v.z + bias.z)));
            v.w = 1.f / (1.f + expf(-(v.w + bias.w)));
            *(float4*)(mod + ((size_t)(b * TLEN + t0 + t)) * HID + hq * 4) = v;
        }
    }
}

// ============================================================
// Fused scan+head (r7 form, measured ~neutral vs split; keeps one
// fewer launch). Unchanged.
// ============================================================
#define SSTEP(CE, CG) { \
    const float ce = (CE), cg = (CG); \
    m1 = 0.9f * m1 + ce; float s1 = ((m1 - 0.7f) >= 0.f) ? 1.f : 0.f; m1 = m1 * (1.f - s1); \
    m2 = 0.8f * m2 + ce; float s2 = ((m2 - 0.5f) >= 0.f) ? 1.f : 0.f; m2 = m2 * (1.f - s2); \
    m3 = 0.6f * m3 + ce; float s3 = ((m3 - 0.3f) >= 0.f) ? 1.f : 0.f; m3 = m3 * (1.f - s3); \
    const float hr = (s1 + s2 + s3) / 3.0f; \
    eta = 0.36f * eta + 0.64f * prev; \
    const float theta = 0.5f + 1.8f * eta - g * cg; \
    ma = 0.8f * ma + hr; \
    const float sa = ((ma - theta) >= 0.f) ? 1.f : 0.f; \
    ma = ma * (1.f - sa); \
    mli = 0.9f * mli + sa; \
    prev = sa; }

__global__ __launch_bounds__(128) void scan_head_kernel(
    float* __restrict__ ws,
    const float* __restrict__ f1w, const float* __restrict__ f1b,
    const float* __restrict__ f2w, const float* __restrict__ f2b,
    float* __restrict__ out)
{
    __shared__ __align__(16) float dps[4][320];
    __shared__ float act[4][128];
    const int tid = threadIdx.x;
    const int grp = tid >> 5, h = tid & 31;
    const int b = blockIdx.x * 4 + grp;

    // ---- scan for (b, h) ----
    {
        const float g = ws[OFF_GAM + h];
        const float* pe = ws + OFF_ENC + (size_t)b * TLEN * HID + h;
        const float* pg = ws + OFF_MOD + (size_t)b * TLEN * HID + h;
        float* dpp = &dps[grp][h * 10];

        float m1 = 0.f, m2 = 0.f, m3 = 0.f, ma = 0.f, eta = 0.f, mli = 0.f, prev = 0.f;
        float acc_lo = 0.f, acc_hi = 0.f;
        float ceA[16], cgA[16], ceB[16], cgB[16];

        #pragma unroll
        for (int i = 0; i < 16; ++i) { ceA[i] = pe[i * HID]; cgA[i] = pg[i * HID]; }

        #pragma unroll 1
        for (int ch = 0; ch < 20; ch += 2) {
            const int baseB = (ch + 1) * 16;
            #pragma unroll
            for (int i = 0; i < 16; ++i) {
                ceB[i] = pe[(baseB + i) * HID];
                cgB[i] = pg[(baseB + i) * HID];
            }
            #pragma unroll
            for (int i = 0; i < 16; ++i) {       // t&31 = i < 16 -> lo
                SSTEP(ceA[i], cgA[i]);
                acc_lo += mli;
            }
            if (ch + 2 < 20) {
                const int baseA = (ch + 2) * 16;
                #pragma unroll
                for (int i = 0; i < 16; ++i) {
                    ceA[i] = pe[(baseA + i) * HID];
                    cgA[i] = pg[(baseA + i) * HID];
                }
            }
            #pragma unroll
            for (int i = 0; i < 16; ++i) {       // t&31 = 16+i -> hi
                SSTEP(ceB[i], cgB[i]);
                acc_hi += mli;
            }
            dpp[ch >> 1] = acc_hi * (1.f / 16.f) - acc_lo * (1.f / 16.f);
            acc_lo = 0.f; acc_hi = 0.f;
        }
    }
    __syncthreads();

    // ---- fc1 + ELU ----
    {
        const int j = tid;
        #pragma unroll 1
        for (int gb = 0; gb < 4; ++gb) {
            const float* dpb = dps[gb];
            float a0 = 0.f, a1 = 0.f, a2 = 0.f, a3 = 0.f;
            #pragma unroll 4
            for (int i = 0; i < 320; i += 4) {
                a0 = fmaf(dpb[i + 0], f1w[(i + 0) * 128 + j], a0);
                a1 = fmaf(dpb[i + 1], f1w[(i + 1) * 128 + j], a1);
                a2 = fmaf(dpb[i + 2], f1w[(i + 2) * 128 + j], a2);
                a3 = fmaf(dpb[i + 3], f1w[(i + 3) * 128 + j], a3);
            }
            float a = f1b[j] + ((a0 + a1) + (a2 + a3));
            act[gb][j] = (a > 0.f) ? a : expm1f(a);   // ELU, alpha=1
        }
    }
    __syncthreads();

    // ---- fc2 ----
    if (tid < 16) {
        const int gb = tid >> 2, j = tid & 3;
        float o = f2b[j];
        for (int jj = 0; jj < 128; ++jj)
            o = fmaf(act[gb][jj], f2w[jj * 4 + j], o);
        out[(blockIdx.x * 4 + gb) * 4 + j] = o;
    }
}

// ============================================================
extern "C" void kernel_launch(void* const* d_in, const int* in_sizes, int n_in,
                              void* d_out, int out_size, void* d_ws, size_t ws_size,
                              hipStream_t stream)
{
    float* ws = (float*)d_ws;

    P29 P;
    for (int k = 0; k < 29; ++k) P.p[k] = (const float*)d_in[k + 2];
    prep_kernel<<<33, 256, 0, stream>>>(P, ws);

    path_both<<<dim3(2 * NT, BSZ), 256, 0, stream>>>(
        (const float*)d_in[0], (const float*)d_in[1], ws);

    scan_head_kernel<<<BSZ / 4, 128, 0, stream>>>(
        ws, (const float*)d_in[27], (const float*)d_in[28],
        (const float*)d_in[29], (const float*)d_in[30], (float*)d_out);
}